// Round 5
// baseline (1253.324 us; speedup 1.0000x reference)
//
#include <hip/hip_runtime.h>
#include <hip/hip_bf16.h>

typedef unsigned short u16;
typedef unsigned int u32;
typedef short short8v __attribute__((ext_vector_type(8)));
typedef float f32x4 __attribute__((ext_vector_type(4)));

#define NN 50000
#define EE 800000
#define PP 65536
// feature widths: IN=H1=H2=128, H3=64; K=3 hops -> concat width 512 (128 f0 + 384 Hcat)

// ---- static device workspace (module-load allocated; ws_size not trusted).
// RULE (r3 post-mortem): device-global addresses never cross the host/device
// boundary — kernels resolve them in device code via compile-time IDs.
__device__ __align__(256) float g_deg_norm[NN];
__device__ __align__(256) int   g_row_ptr[NN + 1];
__device__ __align__(256) int   g_deg[NN];
__device__ __align__(256) int   g_cursor[NN];
__device__ __align__(256) int   g_col[EE];
__device__ __align__(256) float g_wcsr[EE];
__device__ __align__(256) u16   g_Hcat[NN * 384];  // hop slots 1..3 per row (bf16)
__device__ __align__(256) u16   g_Hn0[NN * 128];
__device__ __align__(256) u16   g_Hn1[NN * 128];
__device__ __align__(256) float g_Hfin[NN * 64];   // final h in fp32 for predictor
__device__ int g_f32mode;  // 1 if harness float tensors are float32, 0 if bf16

__device__ __forceinline__ float bf2f(u16 u) {
  union { u32 i; float f; } v;
  v.i = ((u32)u) << 16;
  return v.f;
}
__device__ __forceinline__ u16 f2bf(float f) {
  u32 x = __float_as_uint(f);
  u32 r = (x + 0x7fffu + ((x >> 16) & 1u)) >> 16;  // RNE
  return (u16)r;
}
// adaptive load of harness float tensor element i
__device__ __forceinline__ float ldf(const void* p, int i, int m) {
  return m ? ((const float*)p)[i] : bf2f(((const u16*)p)[i]);
}

// buffer IDs: 0 = runtime ptr arg (x), 1 = Hcat+0, 2 = Hcat+128, 3 = Hn0, 4 = Hn1
template <int ID>
__device__ __forceinline__ const u16* sel_in(const u16* x) {
  if (ID == 0) return x;
  if (ID == 1) return g_Hcat;
  if (ID == 2) return g_Hcat + 128;
  if (ID == 3) return g_Hn0;
  return g_Hn1;
}
template <int ID> __device__ __forceinline__ int sel_stride() {
  return (ID == 1 || ID == 2) ? 384 : 128;
}

// -------------------------------------------------------------- dtype probe
// f32 data read as u16: even indices are low-mantissa noise -> ~44% have bf16
// exponent >= 0x8F (|v|>=2^16). Genuine bf16 N(0,1): zero such patterns.
__global__ void probe_dtype_kernel(const u16* __restrict__ x) {
  __shared__ int cnt;
  if (threadIdx.x == 0) cnt = 0;
  __syncthreads();
  int c = 0;
  for (int i = threadIdx.x; i < 2048; i += 256) {
    u16 u = x[2 * i];
    int e = (u >> 7) & 0xFF;
    if (e >= 0x8F) c++;
  }
  atomicAdd(&cnt, c);
  __syncthreads();
  if (threadIdx.x == 0) g_f32mode = (cnt > 64) ? 1 : 0;
}

// ---------------------------------------------------------------- zero degrees
__global__ void zero_deg_kernel() {
  int i = blockIdx.x * blockDim.x + threadIdx.x;
  if (i < NN) g_deg[i] = 0;
}

// ---------------------------------------------------------------- degree count
__global__ void count_deg_kernel(const int* __restrict__ dst) {
  int e = blockIdx.x * blockDim.x + threadIdx.x;
  if (e < EE) atomicAdd(&g_deg[dst[e]], 1);
}

// ---------------------------------------------- scan: row_ptr, cursor, deg_norm
__global__ __launch_bounds__(1024) void scan_kernel() {
  __shared__ int wsum[16];
  __shared__ int running;
  int tid = threadIdx.x;
  if (tid == 0) running = 0;
  __syncthreads();
  int nchunk = (NN + 1023) >> 10;
  for (int c = 0; c < nchunk; ++c) {
    int i = (c << 10) + tid;
    int v = (i < NN) ? g_deg[i] : 0;
    int x = v;
#pragma unroll
    for (int off = 1; off < 64; off <<= 1) {
      int y = __shfl_up(x, off, 64);
      if ((tid & 63) >= off) x += y;
    }
    int wid = tid >> 6;
    if ((tid & 63) == 63) wsum[wid] = x;
    __syncthreads();
    if (tid == 0) {
      int s = 0;
#pragma unroll
      for (int k = 0; k < 16; ++k) { s += wsum[k]; wsum[k] = s; }  // inclusive
    }
    __syncthreads();
    int base = running + (wid ? wsum[wid - 1] : 0);
    if (i < NN) {
      int excl = base + x - v;
      g_row_ptr[i] = excl;
      g_cursor[i]  = excl;
      g_deg_norm[i] = rsqrtf((float)(v > 0 ? v : 1));
    }
    __syncthreads();
    if (tid == 0) running += wsum[15];
    __syncthreads();
  }
  if (tid == 0) g_row_ptr[NN] = running;
}

// ------------------------------------------------------------------- CSR fill
__global__ void fill_csr_kernel(const int* __restrict__ src, const int* __restrict__ dst,
                                const void* __restrict__ w_edge) {
  int m = g_f32mode;
  int e = blockIdx.x * blockDim.x + threadIdx.x;
  if (e >= EE) return;
  int d = dst[e], s = src[e];
  int slot = atomicAdd(&g_cursor[d], 1);
  g_col[slot] = s;
  g_wcsr[slot] = ldf(w_edge, e, m) * g_deg_norm[s];
}

// ------------------------------------------------------------------- one hop
// out[n][f] = deg_norm[n] * sum_{e in row n} wcsr[e] * in[col[e]][f]
// one wave per node; lane handles 2 features. block = 256 threads = 4 nodes.
template <int IN_ID, int OUT_OFF>
__global__ __launch_bounds__(256) void hop_kernel(const u16* __restrict__ x) {
  int n = blockIdx.x * 4 + (threadIdx.x >> 6);
  if (n >= NN) return;
  int f2 = threadIdx.x & 63;  // features 2*f2, 2*f2+1
  int beg = g_row_ptr[n], end = g_row_ptr[n + 1];
  float a0 = 0.f, a1 = 0.f;
  if (IN_ID == 0 && g_f32mode) {
    const float* in = (const float*)(const void*)x;
    for (int e = beg; e < end; ++e) {
      int s = g_col[e];
      float c = g_wcsr[e];
      const float* p = in + s * 128 + 2 * f2;
      a0 += c * p[0];
      a1 += c * p[1];
    }
  } else {
    const u16* in = sel_in<IN_ID>(x);
    const int in_stride = sel_stride<IN_ID>();
    for (int e = beg; e < end; ++e) {
      int s = g_col[e];
      float c = g_wcsr[e];
      u32 u = *(const u32*)(in + s * in_stride + 2 * f2);
      a0 += c * bf2f((u16)(u & 0xffffu));
      a1 += c * bf2f((u16)(u >> 16));
    }
  }
  float dn = g_deg_norm[n];
  u32 o = (u32)f2bf(a0 * dn) | ((u32)f2bf(a1 * dn) << 16);
  *(u32*)(g_Hcat + OUT_OFF + n * 384 + 2 * f2) = o;
}

// ------------------------------------------------------------------ MFMA GEMM
// C(MxFOUT) = [A0 (Mx128) | g_Hcat (Mx384)] @ B (512xFOUT) + bias, opt ReLU.
// A0_ID: 0 = x (harness, adaptive dtype), 3/4 = internal bf16.
// C_ID: 0 = final layer (writes g_Hfin fp32 + harness out region), 3/4 internal.
template <int FOUT, bool RELU, int A0_ID, int C_ID>
__global__ __launch_bounds__(256) void gemm_tag_kernel(const u16* __restrict__ A0p,
                                                       const void* __restrict__ B,
                                                       const void* __restrict__ bias,
                                                       void* __restrict__ outp) {
  const int M = NN;
  int m = g_f32mode;

  __shared__ __align__(16) u16 lds_b[16][64][8];
  int tid = threadIdx.x;
  int n0 = blockIdx.y * 16;
  // B fragments: (step, lane, j) = B[step*32 + (lane>>4)*8 + j][n0 + (lane&15)]
#pragma unroll
  for (int i = 0; i < 4; ++i) {
    int q = tid + i * 256;
    int stepq = q >> 6, laneq = q & 63;
    int kbase = stepq * 32 + ((laneq >> 4) << 3);
    int nn = n0 + (laneq & 15);
#pragma unroll
    for (int j = 0; j < 8; ++j) lds_b[stepq][laneq][j] = f2bf(ldf(B, (kbase + j) * FOUT + nn, m));
  }
  __syncthreads();

  int lane = tid & 63, wv = tid >> 6;
  int quad = lane >> 4;
  int arow = lane & 15;  // A m-index AND C column index
  int mbase = blockIdx.x * 256 + wv * 64;

  f32x4 acc[4];
#pragma unroll
  for (int r = 0; r < 4; ++r) acc[r] = (f32x4){0.f, 0.f, 0.f, 0.f};

#pragma unroll
  for (int s = 0; s < 16; ++s) {
    short8v b = *(const short8v*)(&lds_b[s][lane][0]);
    int k = s * 32 + quad * 8;
#pragma unroll
    for (int r = 0; r < 4; ++r) {
      int tile = mbase + r * 16;
      if (tile < M) {  // M % 16 == 0 -> wave-uniform guard
        int row = tile + arow;
        short8v a;
        if (k < 128) {
          if (A0_ID == 0 && m) {
            const float* ap = (const float*)(const void*)A0p + row * 128 + k;
#pragma unroll
            for (int j = 0; j < 8; ++j) ((u16*)&a)[j] = f2bf(ap[j]);
          } else {
            const u16* A0 = sel_in<A0_ID>(A0p);
            a = *(const short8v*)(A0 + row * 128 + k);
          }
        } else {
          a = *(const short8v*)(g_Hcat + row * 384 + (k - 128));
        }
        acc[r] = __builtin_amdgcn_mfma_f32_16x16x32_bf16(a, b, acc[r], 0, 0, 0);
      }
    }
  }

  float bn = ldf(bias, n0 + arow, m);
#pragma unroll
  for (int r = 0; r < 4; ++r) {
    int tile = mbase + r * 16;
    if (tile < M) {
#pragma unroll
      for (int i = 0; i < 4; ++i) {
        int row = tile + quad * 4 + i;  // C/D layout: col=lane&15, row=quad*4+i
        float v = acc[r][i] + bn;
        if (RELU) v = v > 0.f ? v : 0.f;
        int ci = row * FOUT + n0 + arow;
        if (C_ID == 0) {
          g_Hfin[ci] = v;
          if (m) ((float*)outp)[2 * PP + ci] = v;
          else   ((u16*)outp)[2 * PP + ci] = f2bf(v);
        } else {
          u16* C = (u16*)sel_in<C_ID>(nullptr);
          C[ci] = f2bf(v);
        }
      }
    }
  }
}

// ------------------------------------------------------------------ predictor
// z = h[s]*h[d] (64) -> leaky(z@P1+b1) (32) -> leaky(@P2+b2) (16) -> @P3+b3 (1)
__global__ __launch_bounds__(256) void predictor_kernel(
    const int* __restrict__ pos_src, const int* __restrict__ pos_dst,
    const int* __restrict__ neg_src, const int* __restrict__ neg_dst,
    const void* __restrict__ P1, const void* __restrict__ pb1, const void* __restrict__ P2,
    const void* __restrict__ pb2, const void* __restrict__ P3, const void* __restrict__ pb3,
    void* __restrict__ out) {
  __shared__ float sP1[64 * 32];
  __shared__ float sP2[32 * 16];
  __shared__ float sP3[16];
  __shared__ float sb1[32], sb2[16], sb3;
  int m = g_f32mode;
  int tid = threadIdx.x;
  for (int i = tid; i < 64 * 32; i += 256) sP1[i] = ldf(P1, i, m);
  for (int i = tid; i < 32 * 16; i += 256) sP2[i] = ldf(P2, i, m);
  if (tid < 16) sP3[tid] = ldf(P3, tid, m);
  if (tid < 32) sb1[tid] = ldf(pb1, tid, m);
  if (tid < 16) sb2[tid] = ldf(pb2, tid, m);
  if (tid == 0) sb3 = ldf(pb3, 0, m);
  __syncthreads();

  int idx = blockIdx.x * 256 + tid;  // [0, 2P)
  int s, d;
  if (idx < PP) { s = pos_src[idx]; d = pos_dst[idx]; }
  else          { s = neg_src[idx - PP]; d = neg_dst[idx - PP]; }

  const float* hs = g_Hfin + s * 64;
  const float* hd = g_Hfin + d * 64;
  float z[64];
#pragma unroll
  for (int j = 0; j < 64; ++j) z[j] = hs[j] * hd[j];
  float z1[32];
#pragma unroll
  for (int j = 0; j < 32; ++j) {
    float a = sb1[j];
#pragma unroll
    for (int k = 0; k < 64; ++k) a += z[k] * sP1[k * 32 + j];
    z1[j] = a > 0.f ? a : 0.2f * a;
  }
  float z2[16];
#pragma unroll
  for (int j = 0; j < 16; ++j) {
    float a = sb2[j];
#pragma unroll
    for (int k = 0; k < 32; ++k) a += z1[k] * sP2[k * 16 + j];
    z2[j] = a > 0.f ? a : 0.2f * a;
  }
  float o = sb3;
#pragma unroll
  for (int k = 0; k < 16; ++k) o += z2[k] * sP3[k];
  if (m) ((float*)out)[idx] = o;
  else   ((u16*)out)[idx] = f2bf(o);
}

// ------------------------------------------------------------------- launch
extern "C" void kernel_launch(void* const* d_in, const int* in_sizes, int n_in,
                              void* d_out, int out_size, void* d_ws, size_t ws_size,
                              hipStream_t stream) {
  const u16* x       = (const u16*)d_in[0];
  const int* src     = (const int*)d_in[1];
  const int* dst     = (const int*)d_in[2];
  const void* w_edge = d_in[3];
  const int* pos_src = (const int*)d_in[4];
  const int* pos_dst = (const int*)d_in[5];
  const int* neg_src = (const int*)d_in[6];
  const int* neg_dst = (const int*)d_in[7];
  const void* W1 = d_in[8];
  const void* b1 = d_in[9];
  const void* W2 = d_in[10];
  const void* b2 = d_in[11];
  const void* W3 = d_in[12];
  const void* b3 = d_in[13];
  const void* P1  = d_in[14];
  const void* pb1 = d_in[15];
  const void* P2  = d_in[16];
  const void* pb2 = d_in[17];
  const void* P3  = d_in[18];
  const void* pb3 = d_in[19];
  (void)d_ws; (void)ws_size; (void)in_sizes; (void)n_in; (void)out_size;

  // --- dtype probe + CSR build ---
  probe_dtype_kernel<<<1, 256, 0, stream>>>(x);
  zero_deg_kernel<<<(NN + 255) / 256, 256, 0, stream>>>();
  count_deg_kernel<<<(EE + 255) / 256, 256, 0, stream>>>(dst);
  scan_kernel<<<1, 1024, 0, stream>>>();
  fill_csr_kernel<<<(EE + 255) / 256, 256, 0, stream>>>(src, dst, w_edge);

  int gHop = (NN + 3) / 4;
  dim3 gGemm128(196, 8), gGemm64(196, 4);

  // --- Layer 1: f0 = x ---
  hop_kernel<0, 0><<<gHop, 256, 0, stream>>>(x);
  hop_kernel<1, 128><<<gHop, 256, 0, stream>>>(x);
  hop_kernel<2, 256><<<gHop, 256, 0, stream>>>(x);
  gemm_tag_kernel<128, true, 0, 3><<<gGemm128, 256, 0, stream>>>(x, W1, b1, nullptr);

  // --- Layer 2: f0 = Hn0 ---
  hop_kernel<3, 0><<<gHop, 256, 0, stream>>>(x);
  hop_kernel<1, 128><<<gHop, 256, 0, stream>>>(x);
  hop_kernel<2, 256><<<gHop, 256, 0, stream>>>(x);
  gemm_tag_kernel<128, true, 3, 4><<<gGemm128, 256, 0, stream>>>(nullptr, W2, b2, nullptr);

  // --- Layer 3: f0 = Hn1, no relu, writes g_Hfin + out h-region ---
  hop_kernel<4, 0><<<gHop, 256, 0, stream>>>(x);
  hop_kernel<1, 128><<<gHop, 256, 0, stream>>>(x);
  hop_kernel<2, 256><<<gHop, 256, 0, stream>>>(x);
  gemm_tag_kernel<64, false, 4, 0><<<gGemm64, 256, 0, stream>>>(nullptr, W3, b3, d_out);

  // --- Predictor (pos+neg fused) ---
  predictor_kernel<<<(2 * PP) / 256, 256, 0, stream>>>(pos_src, pos_dst, neg_src, neg_dst,
                                                       P1, pb1, P2, pb2, P3, pb3, d_out);
}

// Round 6
// 726.978 us; speedup vs baseline: 1.7240x; 1.7240x over previous
//
#include <hip/hip_runtime.h>
#include <hip/hip_bf16.h>

typedef unsigned short u16;
typedef unsigned int u32;
typedef short short8v __attribute__((ext_vector_type(8)));
typedef float f32x4 __attribute__((ext_vector_type(4)));

#define NN 50000
#define EE 800000
#define PP 65536
#define NB 196  // ceil(NN/256)

// ---- static device workspace. RULE (r3): device-global addresses never cross
// the host/device boundary — kernels resolve them via compile-time IDs.
__device__ __align__(256) float g_deg_norm[NN];
__device__ __align__(256) int   g_row_ptr[NN + 1];
__device__ __align__(256) int   g_deg[NN];
__device__ __align__(256) int   g_cursor[NN];
__device__ __align__(256) int   g_bsum[256];
__device__ __align__(256) int   g_boff[256];
__device__ __align__(256) int   g_col[EE];
__device__ __align__(256) float g_wcsr[EE];
__device__ __align__(256) u16   g_X16[NN * 128];   // x pre-converted to bf16
__device__ __align__(256) u16   g_Hcat[NN * 384];  // hop slots 1..3 per row (bf16)
__device__ __align__(256) u16   g_Hn0[NN * 128];
__device__ __align__(256) u16   g_Hn1[NN * 128];
__device__ __align__(256) float g_Hfin[NN * 64];   // final h fp32 for predictor
__device__ __align__(256) u16   g_Bf1[512 * 128];  // W in MFMA B-fragment order
__device__ __align__(256) u16   g_Bf2[512 * 128];
__device__ __align__(256) u16   g_Bf3[512 * 64];
__device__ int g_f32mode;  // 1 if harness float tensors are float32, 0 if bf16

__device__ __forceinline__ float bf2f(u16 u) {
  union { u32 i; float f; } v;
  v.i = ((u32)u) << 16;
  return v.f;
}
__device__ __forceinline__ u16 f2bf(float f) {
  u32 x = __float_as_uint(f);
  u32 r = (x + 0x7fffu + ((x >> 16) & 1u)) >> 16;  // RNE
  return (u16)r;
}
__device__ __forceinline__ float ldf(const void* p, int i, int m) {
  return m ? ((const float*)p)[i] : bf2f(((const u16*)p)[i]);
}

// buffer IDs: 0 = g_X16, 1 = Hcat+0, 2 = Hcat+128, 3 = Hn0, 4 = Hn1
template <int ID>
__device__ __forceinline__ const u16* sel_in() {
  if (ID == 0) return g_X16;
  if (ID == 1) return g_Hcat;
  if (ID == 2) return g_Hcat + 128;
  if (ID == 3) return g_Hn0;
  return g_Hn1;
}
template <int ID>
__device__ __forceinline__ u16* sel_bf() {
  if (ID == 1) return g_Bf1;
  if (ID == 2) return g_Bf2;
  return g_Bf3;
}

// -------------------------------------------------------------- dtype probe
__global__ void probe_dtype_kernel(const u16* __restrict__ x) {
  __shared__ int cnt;
  if (threadIdx.x == 0) cnt = 0;
  __syncthreads();
  int c = 0;
  for (int i = threadIdx.x; i < 2048; i += 256) {
    u16 u = x[2 * i];
    int e = (u >> 7) & 0xFF;
    if (e >= 0x8F) c++;
  }
  atomicAdd(&cnt, c);
  __syncthreads();
  if (threadIdx.x == 0) g_f32mode = (cnt > 64) ? 1 : 0;
}

// ---------------------------------------------------------- x -> bf16 convert
__global__ void convert_x_kernel(const void* __restrict__ x) {
  int m = g_f32mode;
  int i = blockIdx.x * 256 + threadIdx.x;  // u32-pair index
  if (i >= NN * 64) return;
  u32 lo = f2bf(ldf(x, 2 * i, m));
  u32 hi = f2bf(ldf(x, 2 * i + 1, m));
  ((u32*)g_X16)[i] = lo | (hi << 16);
}

// --------------------------------------------- W -> fragment-ordered bf16
// Bf[((kc*4+s)*NT + nt)*64 + lane][j] = B[kc*128 + s*32 + (lane>>4)*8 + j][nt*16 + (lane&15)]
template <int FOUT, int BF_ID>
__global__ void convert_w_kernel(const void* __restrict__ W) {
  constexpr int NT = FOUT / 16;
  int m = g_f32mode;
  int t = blockIdx.x * 256 + threadIdx.x;
  if (t >= 1024 * NT) return;
  int lane = t & 63;
  int rest = t >> 6;
  int nt = rest % NT;
  int s = (rest / NT) % 4;
  int kc = rest / (NT * 4);
  int kbase = kc * 128 + s * 32 + ((lane >> 4) << 3);
  int n = nt * 16 + (lane & 15);
  u16* dst = sel_bf<BF_ID>() + (size_t)t * 8;
#pragma unroll
  for (int j = 0; j < 8; ++j) dst[j] = f2bf(ldf(W, (kbase + j) * FOUT + n, m));
}

// ---------------------------------------------------------------- CSR build
__global__ void zero_deg_kernel() {
  int i = blockIdx.x * blockDim.x + threadIdx.x;
  if (i < NN) g_deg[i] = 0;
}
__global__ void count_deg_kernel(const int* __restrict__ dst) {
  int e = blockIdx.x * blockDim.x + threadIdx.x;
  if (e < EE) atomicAdd(&g_deg[dst[e]], 1);
}
// block partial sums + deg_norm
__global__ __launch_bounds__(256) void deg_partial_kernel() {
  __shared__ int ws[4];
  int b = blockIdx.x, t = threadIdx.x;
  int i = b * 256 + t;
  int v = (i < NN) ? g_deg[i] : 0;
  if (i < NN) g_deg_norm[i] = rsqrtf((float)(v > 0 ? v : 1));
  int x = v;
#pragma unroll
  for (int off = 1; off < 64; off <<= 1) x += __shfl_xor(x, off, 64);
  if ((t & 63) == 0) ws[t >> 6] = x;
  __syncthreads();
  if (t == 0) g_bsum[b] = ws[0] + ws[1] + ws[2] + ws[3];
}
// exclusive scan of the NB partials (single block)
__global__ __launch_bounds__(256) void scan_bsum_kernel() {
  __shared__ int ws[4];
  int t = threadIdx.x;
  int v = (t < NB) ? g_bsum[t] : 0;
  int x = v;
#pragma unroll
  for (int off = 1; off < 64; off <<= 1) {
    int y = __shfl_up(x, off, 64);
    if ((t & 63) >= off) x += y;
  }
  if ((t & 63) == 63) ws[t >> 6] = x;
  __syncthreads();
  int wp = 0;
  if (t >= 64) wp += ws[0];
  if (t >= 128) wp += ws[1];
  if (t >= 192) wp += ws[2];
  if (t < NB) g_boff[t] = wp + x - v;  // exclusive
}
// per-chunk exclusive scan + global offset -> row_ptr, cursor
__global__ __launch_bounds__(256) void rowptr_kernel() {
  __shared__ int ws[4];
  int b = blockIdx.x, t = threadIdx.x;
  int i = b * 256 + t;
  int v = (i < NN) ? g_deg[i] : 0;
  int x = v;
#pragma unroll
  for (int off = 1; off < 64; off <<= 1) {
    int y = __shfl_up(x, off, 64);
    if ((t & 63) >= off) x += y;
  }
  if ((t & 63) == 63) ws[t >> 6] = x;
  __syncthreads();
  int wp = g_boff[b];
  if (t >= 64) wp += ws[0];
  if (t >= 128) wp += ws[1];
  if (t >= 192) wp += ws[2];
  if (i < NN) {
    int excl = wp + x - v;
    g_row_ptr[i] = excl;
    g_cursor[i] = excl;
  }
  if (b == 0 && t == 0) g_row_ptr[NN] = EE;  // total degree == E exactly
}
__global__ void fill_csr_kernel(const int* __restrict__ src, const int* __restrict__ dst,
                                const void* __restrict__ w_edge) {
  int m = g_f32mode;
  int e = blockIdx.x * blockDim.x + threadIdx.x;
  if (e >= EE) return;
  int d = dst[e], s = src[e];
  int slot = atomicAdd(&g_cursor[d], 1);
  g_col[slot] = s;
  g_wcsr[slot] = ldf(w_edge, e, m) * g_deg_norm[s];
}

// ------------------------------------------------------------------- one hop
// out[n][f] = deg_norm[n] * sum_e wcsr[e] * in[col[e]][f]
// one wave per node; lane = 2 features; edge loop unrolled x4 with independent
// accumulators -> 4 outstanding gathers per lane (latency hiding).
template <int IN_ID, int OUT_OFF>
__global__ __launch_bounds__(256) void hop_kernel() {
  int n = blockIdx.x * 4 + (threadIdx.x >> 6);
  if (n >= NN) return;
  int f2 = threadIdx.x & 63;
  constexpr int st = (IN_ID == 1 || IN_ID == 2) ? 384 : 128;
  const u16* inf = sel_in<IN_ID>() + 2 * f2;
  int beg = g_row_ptr[n], end = g_row_ptr[n + 1];
  float a0 = 0.f, a1 = 0.f, b0 = 0.f, b1 = 0.f;
  float c0 = 0.f, c1 = 0.f, d0 = 0.f, d1 = 0.f;
  int e = beg;
  for (; e + 4 <= end; e += 4) {
    int s0 = g_col[e], s1 = g_col[e + 1], s2 = g_col[e + 2], s3 = g_col[e + 3];
    float w0 = g_wcsr[e], w1 = g_wcsr[e + 1], w2 = g_wcsr[e + 2], w3 = g_wcsr[e + 3];
    u32 u0 = *(const u32*)(inf + s0 * st);
    u32 u1 = *(const u32*)(inf + s1 * st);
    u32 u2 = *(const u32*)(inf + s2 * st);
    u32 u3 = *(const u32*)(inf + s3 * st);
    a0 += w0 * bf2f((u16)u0); a1 += w0 * bf2f((u16)(u0 >> 16));
    b0 += w1 * bf2f((u16)u1); b1 += w1 * bf2f((u16)(u1 >> 16));
    c0 += w2 * bf2f((u16)u2); c1 += w2 * bf2f((u16)(u2 >> 16));
    d0 += w3 * bf2f((u16)u3); d1 += w3 * bf2f((u16)(u3 >> 16));
  }
  for (; e < end; ++e) {
    int s0 = g_col[e];
    float w0 = g_wcsr[e];
    u32 u0 = *(const u32*)(inf + s0 * st);
    a0 += w0 * bf2f((u16)u0);
    a1 += w0 * bf2f((u16)(u0 >> 16));
  }
  float dn = g_deg_norm[n];
  float r0 = ((a0 + b0) + (c0 + d0)) * dn;
  float r1 = ((a1 + b1) + (c1 + d1)) * dn;
  *(u32*)(g_Hcat + OUT_OFF + n * 384 + 2 * f2) = (u32)f2bf(r0) | ((u32)f2bf(r1) << 16);
}

// ------------------------------------------------------------------ MFMA GEMM
// C(M x FOUT) = [A0 (Mx128) | g_Hcat (Mx384)] @ B(512xFOUT) + bias, opt ReLU.
// Block = 128 rows x ALL FOUT cols (A read exactly once). 4 waves x 32 rows.
// B from global in fragment order (L2-resident, coalesced 16B/lane). No LDS.
template <int FOUT, bool RELU, int A0_ID, int C_ID, int BF_ID>
__global__ __launch_bounds__(256) void gemm_kernel(const void* __restrict__ bias,
                                                   void* __restrict__ outp) {
  constexpr int NT = FOUT / 16;
  const u16* A0 = sel_in<A0_ID>();
  const u16* Bf = sel_bf<BF_ID>();
  int tid = threadIdx.x;
  int lane = tid & 63, wv = tid >> 6;
  int quad = lane >> 4, arow = lane & 15;
  int mbase = blockIdx.x * 128 + wv * 32;
  bool gu0 = mbase < NN;           // wave-uniform (NN % 16 == 0)
  bool gu1 = (mbase + 16) < NN;
  if (!gu0) return;                // no barriers in kernel -> safe
  int row0 = mbase + arow, row1 = mbase + 16 + arow;

  f32x4 acc[2][NT];
#pragma unroll
  for (int mt = 0; mt < 2; ++mt)
#pragma unroll
    for (int nt = 0; nt < NT; ++nt) acc[mt][nt] = (f32x4){0.f, 0.f, 0.f, 0.f};

#pragma unroll
  for (int kc = 0; kc < 4; ++kc) {
#pragma unroll
    for (int s = 0; s < 4; ++s) {
      int ko = s * 32 + quad * 8;
      short8v av0, av1;
      if (kc == 0) {
        av0 = *(const short8v*)(A0 + row0 * 128 + ko);
        if (gu1) av1 = *(const short8v*)(A0 + row1 * 128 + ko);
      } else {
        av0 = *(const short8v*)(g_Hcat + row0 * 384 + (kc - 1) * 128 + ko);
        if (gu1) av1 = *(const short8v*)(g_Hcat + row1 * 384 + (kc - 1) * 128 + ko);
      }
      const u16* bp = Bf + (size_t)(((kc * 4 + s) * NT) * 64 + lane) * 8;
#pragma unroll
      for (int nt = 0; nt < NT; ++nt) {
        short8v b = *(const short8v*)(bp + nt * 64 * 8);
        acc[0][nt] = __builtin_amdgcn_mfma_f32_16x16x32_bf16(av0, b, acc[0][nt], 0, 0, 0);
        if (gu1) acc[1][nt] = __builtin_amdgcn_mfma_f32_16x16x32_bf16(av1, b, acc[1][nt], 0, 0, 0);
      }
    }
  }

  int m = g_f32mode;
  float bn[NT];
#pragma unroll
  for (int nt = 0; nt < NT; ++nt) bn[nt] = ldf(bias, nt * 16 + arow, m);
#pragma unroll
  for (int mt = 0; mt < 2; ++mt) {
    if (mt == 1 && !gu1) break;
#pragma unroll
    for (int i = 0; i < 4; ++i) {
      int row = mbase + mt * 16 + quad * 4 + i;  // C/D: col=lane&15, row=quad*4+reg
#pragma unroll
      for (int nt = 0; nt < NT; ++nt) {
        float v = acc[mt][nt][i] + bn[nt];
        if (RELU) v = v > 0.f ? v : 0.f;
        int ci = row * FOUT + nt * 16 + arow;
        if (C_ID == 0) {
          g_Hfin[ci] = v;
          if (m) ((float*)outp)[2 * PP + ci] = v;
          else   ((u16*)outp)[2 * PP + ci] = f2bf(v);
        } else {
          u16* C = (u16*)sel_in<C_ID>();
          C[ci] = f2bf(v);
        }
      }
    }
  }
}

// ------------------------------------------------------------------ predictor
__global__ __launch_bounds__(256) void predictor_kernel(
    const int* __restrict__ pos_src, const int* __restrict__ pos_dst,
    const int* __restrict__ neg_src, const int* __restrict__ neg_dst,
    const void* __restrict__ P1, const void* __restrict__ pb1, const void* __restrict__ P2,
    const void* __restrict__ pb2, const void* __restrict__ P3, const void* __restrict__ pb3,
    void* __restrict__ out) {
  __shared__ float sP1[64 * 32];
  __shared__ float sP2[32 * 16];
  __shared__ float sP3[16];
  __shared__ float sb1[32], sb2[16], sb3;
  int m = g_f32mode;
  int tid = threadIdx.x;
  for (int i = tid; i < 64 * 32; i += 256) sP1[i] = ldf(P1, i, m);
  for (int i = tid; i < 32 * 16; i += 256) sP2[i] = ldf(P2, i, m);
  if (tid < 16) sP3[tid] = ldf(P3, tid, m);
  if (tid < 32) sb1[tid] = ldf(pb1, tid, m);
  if (tid < 16) sb2[tid] = ldf(pb2, tid, m);
  if (tid == 0) sb3 = ldf(pb3, 0, m);
  __syncthreads();

  int idx = blockIdx.x * 256 + tid;  // [0, 2P)
  int s, d;
  if (idx < PP) { s = pos_src[idx]; d = pos_dst[idx]; }
  else          { s = neg_src[idx - PP]; d = neg_dst[idx - PP]; }

  const float* hs = g_Hfin + s * 64;
  const float* hd = g_Hfin + d * 64;
  float z[64];
#pragma unroll
  for (int j = 0; j < 64; ++j) z[j] = hs[j] * hd[j];
  float z1[32];
#pragma unroll
  for (int j = 0; j < 32; ++j) {
    float a = sb1[j];
#pragma unroll
    for (int k = 0; k < 64; ++k) a += z[k] * sP1[k * 32 + j];
    z1[j] = a > 0.f ? a : 0.2f * a;
  }
  float z2[16];
#pragma unroll
  for (int j = 0; j < 16; ++j) {
    float a = sb2[j];
#pragma unroll
    for (int k = 0; k < 32; ++k) a += z1[k] * sP2[k * 16 + j];
    z2[j] = a > 0.f ? a : 0.2f * a;
  }
  float o = sb3;
#pragma unroll
  for (int k = 0; k < 16; ++k) o += z2[k] * sP3[k];
  if (m) ((float*)out)[idx] = o;
  else   ((u16*)out)[idx] = f2bf(o);
}

// ------------------------------------------------------------------- launch
extern "C" void kernel_launch(void* const* d_in, const int* in_sizes, int n_in,
                              void* d_out, int out_size, void* d_ws, size_t ws_size,
                              hipStream_t stream) {
  const u16* x       = (const u16*)d_in[0];
  const int* src     = (const int*)d_in[1];
  const int* dst     = (const int*)d_in[2];
  const void* w_edge = d_in[3];
  const int* pos_src = (const int*)d_in[4];
  const int* pos_dst = (const int*)d_in[5];
  const int* neg_src = (const int*)d_in[6];
  const int* neg_dst = (const int*)d_in[7];
  const void* W1 = d_in[8];
  const void* b1 = d_in[9];
  const void* W2 = d_in[10];
  const void* b2 = d_in[11];
  const void* W3 = d_in[12];
  const void* b3 = d_in[13];
  const void* P1  = d_in[14];
  const void* pb1 = d_in[15];
  const void* P2  = d_in[16];
  const void* pb2 = d_in[17];
  const void* P3  = d_in[18];
  const void* pb3 = d_in[19];
  (void)d_ws; (void)ws_size; (void)in_sizes; (void)n_in; (void)out_size;

  // --- probe + pre-conversion + CSR build ---
  probe_dtype_kernel<<<1, 256, 0, stream>>>(x);
  convert_x_kernel<<<(NN * 64 + 255) / 256, 256, 0, stream>>>(x);
  convert_w_kernel<128, 1><<<32, 256, 0, stream>>>(W1);
  convert_w_kernel<128, 2><<<32, 256, 0, stream>>>(W2);
  convert_w_kernel<64, 3><<<16, 256, 0, stream>>>(W3);
  zero_deg_kernel<<<(NN + 255) / 256, 256, 0, stream>>>();
  count_deg_kernel<<<(EE + 255) / 256, 256, 0, stream>>>(dst);
  deg_partial_kernel<<<NB, 256, 0, stream>>>();
  scan_bsum_kernel<<<1, 256, 0, stream>>>();
  rowptr_kernel<<<NB, 256, 0, stream>>>();
  fill_csr_kernel<<<(EE + 255) / 256, 256, 0, stream>>>(src, dst, w_edge);

  int gHop = (NN + 3) / 4;
  int gGemm = (NN + 127) / 128;

  // --- Layer 1: f0 = x(bf16) ---
  hop_kernel<0, 0><<<gHop, 256, 0, stream>>>();
  hop_kernel<1, 128><<<gHop, 256, 0, stream>>>();
  hop_kernel<2, 256><<<gHop, 256, 0, stream>>>();
  gemm_kernel<128, true, 0, 3, 1><<<gGemm, 256, 0, stream>>>(b1, nullptr);

  // --- Layer 2: f0 = Hn0 ---
  hop_kernel<3, 0><<<gHop, 256, 0, stream>>>();
  hop_kernel<1, 128><<<gHop, 256, 0, stream>>>();
  hop_kernel<2, 256><<<gHop, 256, 0, stream>>>();
  gemm_kernel<128, true, 3, 4, 2><<<gGemm, 256, 0, stream>>>(b2, nullptr);

  // --- Layer 3: f0 = Hn1, no relu, writes g_Hfin + out h-region ---
  hop_kernel<4, 0><<<gHop, 256, 0, stream>>>();
  hop_kernel<1, 128><<<gHop, 256, 0, stream>>>();
  hop_kernel<2, 256><<<gHop, 256, 0, stream>>>();
  gemm_kernel<64, false, 4, 0, 3><<<gGemm, 256, 0, stream>>>(b3, d_out);

  // --- Predictor (pos+neg fused) ---
  predictor_kernel<<<(2 * PP) / 256, 256, 0, stream>>>(pos_src, pos_dst, neg_src, neg_dst,
                                                       P1, pb1, P2, pb2, P3, pb3, d_out);
}

// Round 7
// 694.851 us; speedup vs baseline: 1.8037x; 1.0462x over previous
//
#include <hip/hip_runtime.h>
#include <hip/hip_bf16.h>

typedef unsigned short u16;
typedef unsigned int u32;
typedef short short8v __attribute__((ext_vector_type(8)));
typedef float f32x4 __attribute__((ext_vector_type(4)));

#define NN 50000
#define EE 800000
#define PP 65536
#define NB 196  // ceil(NN/256)

// ---- static device workspace. RULE (r3): device-global addresses never cross
// the host/device boundary — kernels resolve them via compile-time IDs.
__device__ __align__(256) float g_deg_norm[NN];
__device__ __align__(256) int   g_row_ptr[NN + 1];
__device__ __align__(256) int   g_deg[NN];
__device__ __align__(256) int   g_cursor[NN];
__device__ __align__(256) int   g_bsum[256];
__device__ __align__(256) int   g_boff[256];
__device__ __align__(256) int2  g_ecw[EE];         // (col, w-bits) fused pair
__device__ __align__(256) u16   g_X16[NN * 128];   // x pre-converted to bf16
__device__ __align__(256) u16   g_H1[NN * 128];    // hop outputs, stride 128
__device__ __align__(256) u16   g_H2[NN * 128];
__device__ __align__(256) u16   g_H3[NN * 128];
__device__ __align__(256) u16   g_Hn0[NN * 128];
__device__ __align__(256) u16   g_Hn1[NN * 128];
__device__ __align__(256) float g_Hfin[NN * 64];   // final h fp32 for predictor
__device__ __align__(256) u16   g_Bf1[512 * 128];  // W in MFMA B-fragment order
__device__ __align__(256) u16   g_Bf2[512 * 128];
__device__ __align__(256) u16   g_Bf3[512 * 64];
__device__ int g_f32mode;  // 1 if harness float tensors are float32, 0 if bf16

__device__ __forceinline__ float bf2f(u16 u) {
  union { u32 i; float f; } v;
  v.i = ((u32)u) << 16;
  return v.f;
}
__device__ __forceinline__ u16 f2bf(float f) {
  u32 x = __float_as_uint(f);
  u32 r = (x + 0x7fffu + ((x >> 16) & 1u)) >> 16;  // RNE
  return (u16)r;
}
__device__ __forceinline__ float ldf(const void* p, int i, int m) {
  return m ? ((const float*)p)[i] : bf2f(((const u16*)p)[i]);
}

// buffer IDs: 0 = X16, 3 = Hn0, 4 = Hn1, 5 = H1, 6 = H2, 7 = H3 (all stride 128)
template <int ID>
__device__ __forceinline__ u16* sel_buf() {
  if (ID == 0) return g_X16;
  if (ID == 3) return g_Hn0;
  if (ID == 4) return g_Hn1;
  if (ID == 5) return g_H1;
  if (ID == 6) return g_H2;
  return g_H3;
}
template <int ID>
__device__ __forceinline__ u16* sel_bf() {
  if (ID == 1) return g_Bf1;
  if (ID == 2) return g_Bf2;
  return g_Bf3;
}

// -------------------------------------------------------------- dtype probe
__global__ void probe_dtype_kernel(const u16* __restrict__ x) {
  __shared__ int cnt;
  if (threadIdx.x == 0) cnt = 0;
  __syncthreads();
  int c = 0;
  for (int i = threadIdx.x; i < 2048; i += 256) {
    u16 u = x[2 * i];
    int e = (u >> 7) & 0xFF;
    if (e >= 0x8F) c++;
  }
  atomicAdd(&cnt, c);
  __syncthreads();
  if (threadIdx.x == 0) g_f32mode = (cnt > 64) ? 1 : 0;
}

// ---------------------------------------------------------- x -> bf16 convert
__global__ void convert_x_kernel(const void* __restrict__ x) {
  int m = g_f32mode;
  int i = blockIdx.x * 256 + threadIdx.x;  // u32-pair index
  if (i >= NN * 64) return;
  u32 lo = f2bf(ldf(x, 2 * i, m));
  u32 hi = f2bf(ldf(x, 2 * i + 1, m));
  ((u32*)g_X16)[i] = lo | (hi << 16);
}

// --------------------------------------------- W -> fragment-ordered bf16
// Bf[((kc*4+s)*NT + nt)*64 + lane][j] = B[kc*128 + s*32 + (lane>>4)*8 + j][nt*16 + (lane&15)]
template <int FOUT, int BF_ID>
__global__ void convert_w_kernel(const void* __restrict__ W) {
  constexpr int NT = FOUT / 16;
  int m = g_f32mode;
  int t = blockIdx.x * 256 + threadIdx.x;
  if (t >= 1024 * NT) return;
  int lane = t & 63;
  int rest = t >> 6;
  int nt = rest % NT;
  int s = (rest / NT) % 4;
  int kc = rest / (NT * 4);
  int kbase = kc * 128 + s * 32 + ((lane >> 4) << 3);
  int n = nt * 16 + (lane & 15);
  u16* dst = sel_bf<BF_ID>() + (size_t)t * 8;
#pragma unroll
  for (int j = 0; j < 8; ++j) dst[j] = f2bf(ldf(W, (kbase + j) * FOUT + n, m));
}

// ---------------------------------------------------------------- CSR build
__global__ void zero_deg_kernel() {
  int i = blockIdx.x * blockDim.x + threadIdx.x;
  if (i < NN) g_deg[i] = 0;
}
__global__ void count_deg_kernel(const int* __restrict__ dst) {
  int e = blockIdx.x * blockDim.x + threadIdx.x;
  if (e < EE) atomicAdd(&g_deg[dst[e]], 1);
}
__global__ __launch_bounds__(256) void deg_partial_kernel() {
  __shared__ int ws[4];
  int b = blockIdx.x, t = threadIdx.x;
  int i = b * 256 + t;
  int v = (i < NN) ? g_deg[i] : 0;
  if (i < NN) g_deg_norm[i] = rsqrtf((float)(v > 0 ? v : 1));
  int x = v;
#pragma unroll
  for (int off = 1; off < 64; off <<= 1) x += __shfl_xor(x, off, 64);
  if ((t & 63) == 0) ws[t >> 6] = x;
  __syncthreads();
  if (t == 0) g_bsum[b] = ws[0] + ws[1] + ws[2] + ws[3];
}
__global__ __launch_bounds__(256) void scan_bsum_kernel() {
  __shared__ int ws[4];
  int t = threadIdx.x;
  int v = (t < NB) ? g_bsum[t] : 0;
  int x = v;
#pragma unroll
  for (int off = 1; off < 64; off <<= 1) {
    int y = __shfl_up(x, off, 64);
    if ((t & 63) >= off) x += y;
  }
  if ((t & 63) == 63) ws[t >> 6] = x;
  __syncthreads();
  int wp = 0;
  if (t >= 64) wp += ws[0];
  if (t >= 128) wp += ws[1];
  if (t >= 192) wp += ws[2];
  if (t < NB) g_boff[t] = wp + x - v;  // exclusive
}
__global__ __launch_bounds__(256) void rowptr_kernel() {
  __shared__ int ws[4];
  int b = blockIdx.x, t = threadIdx.x;
  int i = b * 256 + t;
  int v = (i < NN) ? g_deg[i] : 0;
  int x = v;
#pragma unroll
  for (int off = 1; off < 64; off <<= 1) {
    int y = __shfl_up(x, off, 64);
    if ((t & 63) >= off) x += y;
  }
  if ((t & 63) == 63) ws[t >> 6] = x;
  __syncthreads();
  int wp = g_boff[b];
  if (t >= 64) wp += ws[0];
  if (t >= 128) wp += ws[1];
  if (t >= 192) wp += ws[2];
  if (i < NN) {
    int excl = wp + x - v;
    g_row_ptr[i] = excl;
    g_cursor[i] = excl;
  }
  if (b == 0 && t == 0) g_row_ptr[NN] = EE;
}
// fused (col, w) pair: ONE 8-B scattered store per edge instead of two 4-B
// stores into two arrays (r6 profile: 82 MB write-allocate traffic -> ~45 MB).
__global__ void fill_csr_kernel(const int* __restrict__ src, const int* __restrict__ dst,
                                const void* __restrict__ w_edge) {
  int m = g_f32mode;
  int e = blockIdx.x * blockDim.x + threadIdx.x;
  if (e >= EE) return;
  int d = dst[e], s = src[e];
  int slot = atomicAdd(&g_cursor[d], 1);
  float w = ldf(w_edge, e, m) * g_deg_norm[s];
  g_ecw[slot] = make_int2(s, __float_as_int(w));
}

// ------------------------------------------------------------------- one hop
// out[n][f] = deg_norm[n] * sum_e w[e] * in[col[e]][f]
// one wave per node (4 nodes/block); lane = 2 features; 8/4/1 unroll cascade
// with 16 independent accumulators -> 8 gathers in flight per wave.
template <int IN_ID, int OUT_ID>
__global__ __launch_bounds__(256) void hop_kernel() {
  int n = blockIdx.x * 4 + (threadIdx.x >> 6);
  if (n >= NN) return;
  int f2 = threadIdx.x & 63;
  const u16* inf = sel_buf<IN_ID>() + 2 * f2;
  int beg = g_row_ptr[n], end = g_row_ptr[n + 1];
  float a0[8], a1[8];
#pragma unroll
  for (int i = 0; i < 8; ++i) { a0[i] = 0.f; a1[i] = 0.f; }
  int e = beg;
  for (; e + 8 <= end; e += 8) {
    int2 p[8];
#pragma unroll
    for (int i = 0; i < 8; ++i) p[i] = g_ecw[e + i];
    u32 u[8];
#pragma unroll
    for (int i = 0; i < 8; ++i) u[i] = *(const u32*)(inf + p[i].x * 128);
#pragma unroll
    for (int i = 0; i < 8; ++i) {
      float w = __int_as_float(p[i].y);
      a0[i] += w * bf2f((u16)u[i]);
      a1[i] += w * bf2f((u16)(u[i] >> 16));
    }
  }
  for (; e + 4 <= end; e += 4) {
    int2 p[4];
#pragma unroll
    for (int i = 0; i < 4; ++i) p[i] = g_ecw[e + i];
    u32 u[4];
#pragma unroll
    for (int i = 0; i < 4; ++i) u[i] = *(const u32*)(inf + p[i].x * 128);
#pragma unroll
    for (int i = 0; i < 4; ++i) {
      float w = __int_as_float(p[i].y);
      a0[i] += w * bf2f((u16)u[i]);
      a1[i] += w * bf2f((u16)(u[i] >> 16));
    }
  }
  for (; e < end; ++e) {
    int2 p = g_ecw[e];
    u32 u = *(const u32*)(inf + p.x * 128);
    float w = __int_as_float(p.y);
    a0[0] += w * bf2f((u16)u);
    a1[0] += w * bf2f((u16)(u >> 16));
  }
  float s0 = ((a0[0] + a0[1]) + (a0[2] + a0[3])) + ((a0[4] + a0[5]) + (a0[6] + a0[7]));
  float s1 = ((a1[0] + a1[1]) + (a1[2] + a1[3])) + ((a1[4] + a1[5]) + (a1[6] + a1[7]));
  float dn = g_deg_norm[n];
  *(u32*)(sel_buf<OUT_ID>() + n * 128 + 2 * f2) =
      (u32)f2bf(s0 * dn) | ((u32)f2bf(s1 * dn) << 16);
}

// ------------------------------------------------------------------ MFMA GEMM
// C(M x FOUT) = [f0 | H1 | H2 | H3] (Mx512, all stride 128) @ B + bias, opt ReLU.
// Block = 128 rows x ALL FOUT cols (A read exactly once). 4 waves x 32 rows.
// B from global in fragment order (L2-resident, coalesced 16B/lane). No LDS.
template <int FOUT, bool RELU, int A0_ID, int C_ID, int BF_ID>
__global__ __launch_bounds__(256) void gemm_kernel(const void* __restrict__ bias,
                                                   void* __restrict__ outp) {
  constexpr int NT = FOUT / 16;
  const u16* Bf = sel_bf<BF_ID>();
  int tid = threadIdx.x;
  int lane = tid & 63, wv = tid >> 6;
  int quad = lane >> 4, arow = lane & 15;
  int mbase = blockIdx.x * 128 + wv * 32;
  bool gu0 = mbase < NN;           // wave-uniform (NN % 16 == 0)
  bool gu1 = (mbase + 16) < NN;
  if (!gu0) return;                // no barriers in kernel -> safe
  int row0 = mbase + arow, row1 = mbase + 16 + arow;

  f32x4 acc[2][NT];
#pragma unroll
  for (int mt = 0; mt < 2; ++mt)
#pragma unroll
    for (int nt = 0; nt < NT; ++nt) acc[mt][nt] = (f32x4){0.f, 0.f, 0.f, 0.f};

#pragma unroll
  for (int kc = 0; kc < 4; ++kc) {
    const u16* base = (kc == 0) ? sel_buf<A0_ID>() : (kc == 1) ? g_H1 : (kc == 2) ? g_H2 : g_H3;
#pragma unroll
    for (int s = 0; s < 4; ++s) {
      int ko = s * 32 + quad * 8;
      short8v av0 = *(const short8v*)(base + row0 * 128 + ko);
      short8v av1;
      if (gu1) av1 = *(const short8v*)(base + row1 * 128 + ko);
      const u16* bp = Bf + (size_t)(((kc * 4 + s) * NT) * 64 + lane) * 8;
#pragma unroll
      for (int nt = 0; nt < NT; ++nt) {
        short8v b = *(const short8v*)(bp + nt * 64 * 8);
        acc[0][nt] = __builtin_amdgcn_mfma_f32_16x16x32_bf16(av0, b, acc[0][nt], 0, 0, 0);
        if (gu1) acc[1][nt] = __builtin_amdgcn_mfma_f32_16x16x32_bf16(av1, b, acc[1][nt], 0, 0, 0);
      }
    }
  }

  int m = g_f32mode;
  float bn[NT];
#pragma unroll
  for (int nt = 0; nt < NT; ++nt) bn[nt] = ldf(bias, nt * 16 + arow, m);
#pragma unroll
  for (int mt = 0; mt < 2; ++mt) {
    if (mt == 1 && !gu1) break;
#pragma unroll
    for (int i = 0; i < 4; ++i) {
      int row = mbase + mt * 16 + quad * 4 + i;  // C/D: col=lane&15, row=quad*4+reg
#pragma unroll
      for (int nt = 0; nt < NT; ++nt) {
        float v = acc[mt][nt][i] + bn[nt];
        if (RELU) v = v > 0.f ? v : 0.f;
        int ci = row * FOUT + nt * 16 + arow;
        if (C_ID == 0) {
          g_Hfin[ci] = v;
          if (m) ((float*)outp)[2 * PP + ci] = v;
          else   ((u16*)outp)[2 * PP + ci] = f2bf(v);
        } else {
          sel_buf<C_ID>()[ci] = f2bf(v);
        }
      }
    }
  }
}

// ------------------------------------------------------------------ predictor
__global__ __launch_bounds__(256) void predictor_kernel(
    const int* __restrict__ pos_src, const int* __restrict__ pos_dst,
    const int* __restrict__ neg_src, const int* __restrict__ neg_dst,
    const void* __restrict__ P1, const void* __restrict__ pb1, const void* __restrict__ P2,
    const void* __restrict__ pb2, const void* __restrict__ P3, const void* __restrict__ pb3,
    void* __restrict__ out) {
  __shared__ float sP1[64 * 32];
  __shared__ float sP2[32 * 16];
  __shared__ float sP3[16];
  __shared__ float sb1[32], sb2[16], sb3;
  int m = g_f32mode;
  int tid = threadIdx.x;
  for (int i = tid; i < 64 * 32; i += 256) sP1[i] = ldf(P1, i, m);
  for (int i = tid; i < 32 * 16; i += 256) sP2[i] = ldf(P2, i, m);
  if (tid < 16) sP3[tid] = ldf(P3, tid, m);
  if (tid < 32) sb1[tid] = ldf(pb1, tid, m);
  if (tid < 16) sb2[tid] = ldf(pb2, tid, m);
  if (tid == 0) sb3 = ldf(pb3, 0, m);
  __syncthreads();

  int idx = blockIdx.x * 256 + tid;  // [0, 2P)
  int s, d;
  if (idx < PP) { s = pos_src[idx]; d = pos_dst[idx]; }
  else          { s = neg_src[idx - PP]; d = neg_dst[idx - PP]; }

  const float* hs = g_Hfin + s * 64;
  const float* hd = g_Hfin + d * 64;
  float z[64];
#pragma unroll
  for (int j = 0; j < 64; ++j) z[j] = hs[j] * hd[j];
  float z1[32];
#pragma unroll
  for (int j = 0; j < 32; ++j) {
    float a = sb1[j];
#pragma unroll
    for (int k = 0; k < 64; ++k) a += z[k] * sP1[k * 32 + j];
    z1[j] = a > 0.f ? a : 0.2f * a;
  }
  float z2[16];
#pragma unroll
  for (int j = 0; j < 16; ++j) {
    float a = sb2[j];
#pragma unroll
    for (int k = 0; k < 32; ++k) a += z1[k] * sP2[k * 16 + j];
    z2[j] = a > 0.f ? a : 0.2f * a;
  }
  float o = sb3;
#pragma unroll
  for (int k = 0; k < 16; ++k) o += z2[k] * sP3[k];
  if (m) ((float*)out)[idx] = o;
  else   ((u16*)out)[idx] = f2bf(o);
}

// ------------------------------------------------------------------- launch
extern "C" void kernel_launch(void* const* d_in, const int* in_sizes, int n_in,
                              void* d_out, int out_size, void* d_ws, size_t ws_size,
                              hipStream_t stream) {
  const u16* x       = (const u16*)d_in[0];
  const int* src     = (const int*)d_in[1];
  const int* dst     = (const int*)d_in[2];
  const void* w_edge = d_in[3];
  const int* pos_src = (const int*)d_in[4];
  const int* pos_dst = (const int*)d_in[5];
  const int* neg_src = (const int*)d_in[6];
  const int* neg_dst = (const int*)d_in[7];
  const void* W1 = d_in[8];
  const void* b1 = d_in[9];
  const void* W2 = d_in[10];
  const void* b2 = d_in[11];
  const void* W3 = d_in[12];
  const void* b3 = d_in[13];
  const void* P1  = d_in[14];
  const void* pb1 = d_in[15];
  const void* P2  = d_in[16];
  const void* pb2 = d_in[17];
  const void* P3  = d_in[18];
  const void* pb3 = d_in[19];
  (void)d_ws; (void)ws_size; (void)in_sizes; (void)n_in; (void)out_size;

  // --- probe + pre-conversion + CSR build ---
  probe_dtype_kernel<<<1, 256, 0, stream>>>(x);
  convert_x_kernel<<<(NN * 64 + 255) / 256, 256, 0, stream>>>(x);
  convert_w_kernel<128, 1><<<32, 256, 0, stream>>>(W1);
  convert_w_kernel<128, 2><<<32, 256, 0, stream>>>(W2);
  convert_w_kernel<64, 3><<<16, 256, 0, stream>>>(W3);
  zero_deg_kernel<<<(NN + 255) / 256, 256, 0, stream>>>();
  count_deg_kernel<<<(EE + 255) / 256, 256, 0, stream>>>(dst);
  deg_partial_kernel<<<NB, 256, 0, stream>>>();
  scan_bsum_kernel<<<1, 256, 0, stream>>>();
  rowptr_kernel<<<NB, 256, 0, stream>>>();
  fill_csr_kernel<<<(EE + 255) / 256, 256, 0, stream>>>(src, dst, w_edge);

  int gHop = (NN + 3) / 4;
  int gGemm = (NN + 127) / 128;

  // --- Layer 1: f0 = x(bf16) ---
  hop_kernel<0, 5><<<gHop, 256, 0, stream>>>();
  hop_kernel<5, 6><<<gHop, 256, 0, stream>>>();
  hop_kernel<6, 7><<<gHop, 256, 0, stream>>>();
  gemm_kernel<128, true, 0, 3, 1><<<gGemm, 256, 0, stream>>>(b1, nullptr);

  // --- Layer 2: f0 = Hn0 ---
  hop_kernel<3, 5><<<gHop, 256, 0, stream>>>();
  hop_kernel<5, 6><<<gHop, 256, 0, stream>>>();
  hop_kernel<6, 7><<<gHop, 256, 0, stream>>>();
  gemm_kernel<128, true, 3, 4, 2><<<gGemm, 256, 0, stream>>>(b2, nullptr);

  // --- Layer 3: f0 = Hn1, no relu, writes g_Hfin + out h-region ---
  hop_kernel<4, 5><<<gHop, 256, 0, stream>>>();
  hop_kernel<5, 6><<<gHop, 256, 0, stream>>>();
  hop_kernel<6, 7><<<gHop, 256, 0, stream>>>();
  gemm_kernel<64, false, 4, 0, 3><<<gGemm, 256, 0, stream>>>(b3, d_out);

  // --- Predictor (pos+neg fused) ---
  predictor_kernel<<<(2 * PP) / 256, 256, 0, stream>>>(pos_src, pos_dst, neg_src, neg_dst,
                                                       P1, pb1, P2, pb2, P3, pb3, d_out);
}